// Round 7
// baseline (453.867 us; speedup 1.0000x reference)
//
#include <hip/hip_runtime.h>

constexpr int K = 1024;        // num codes
constexpr int D = 64;          // dim
constexpr int N = 131072;      // 32*4096 points
constexpr float INV_N = 1.0f / 131072.0f;
constexpr float INV_ELEMS = 1.0f / 8388608.0f;  // N*D
constexpr float LOG2E = 1.4426950408889634f;
constexpr float DELTA = 0.01f;  // refine margin in log2e-scaled units

// Output layout (flat float32, return order)
constexpr size_t O_QST  = 0;          // [N*D] quantized_st
constexpr size_t O_LOSS = 8388608;    // [1]
constexpr size_t O_IDX  = 8388609;    // [N]
constexpr size_t O_CBL  = 8519681;    // [1]
constexpr size_t O_CML  = 8519682;    // [1]
constexpr size_t O_PPL  = 8519683;    // [1]
constexpr size_t O_USG  = 8519684;    // [1024]
constexpr size_t O_SU   = 8520708;    // [1024]

// Workspace (float offsets), ~5.6 MB total:
//  [0,1024)        cn     raw fp32 codebook norms (exact rescan)
//  [1024,2048)     counts
//  [2048,3072)     susum
//  [3072,3328)     sqp    spread sqerr partials
//  [3328]          nflag  (int) flagged-point counter
//  [3584,4608)     ncn2   -cn * log2e (acc-init)
//  [4608,37376)    chA    bf16 hi split of codebook*log2e, frag layout
//  [37376,70144)   clA    bf16 lo split
//  [70144,201216)  ctA    per-point ct2 = -log2(Z')
//  [201216,332288) list   (int) flagged point ids
//  [332288,1380864) part  float4[N*2]: per (point, cb-half) partials
//                         (Z, b1, b2, bi)

// qst slots double as z-frag storage between p1 and epi:
// tile t (32 points): shorts base = t*4096; hi frag at (ks*64+lane)*8,
// lo frag at 2048 + (ks*64+lane)*8.  Holds split of (+2*z).

typedef __attribute__((ext_vector_type(8))) short bf16x8;
typedef __attribute__((ext_vector_type(16))) float f32x16;

__device__ inline unsigned short f2bf(float f) {  // RTNE fp32->bf16
  unsigned u = __float_as_uint(f);
  return (unsigned short)((u + 0x7FFF + ((u >> 16) & 1)) >> 16);
}
__device__ inline float bf2f(unsigned short h) {
  return __uint_as_float(((unsigned)h) << 16);
}

// ---------------------------------------------------------------------------
// Fused norms + frag prep: wave = one code (64 consecutive gids).
__global__ __launch_bounds__(256) void vq_prep(const float* __restrict__ cb,
                                               float* __restrict__ cn,
                                               float* __restrict__ ncn2,
                                               short* __restrict__ chA,
                                               short* __restrict__ clA) {
  const int gid = blockIdx.x * 256 + threadIdx.x;  // 65536
  const int c = gid >> 6, d = gid & 63;            // c wave-uniform
  float v = cb[gid];
  float s = v * v;
#pragma unroll
  for (int o = 32; o > 0; o >>= 1) s += __shfl_xor(s, o, 64);
  if (d == 0) {
    cn[c] = s;
    ncn2[c] = -s * LOG2E;
  }
  float vb = v * LOG2E;
  unsigned short h = f2bf(vb);
  unsigned short l = f2bf(vb - bf2f(h));
  const int tile = c >> 5, ks = d >> 4, hff = (d >> 3) & 1, j = d & 7;
  const int lane = hff * 32 + (c & 31);
  const size_t off = ((size_t)((tile * 4 + ks) * 64 + lane)) * 8 + j;
  chA[off] = (short)h;
  clA[off] = (short)l;
}

// ---------------------------------------------------------------------------
// Pass 1: block = 32 points x HALF the codebook (h = blockIdx&1).
// acc = -s = 2z.c*log2e - cn2, single fp32 MFMA accumulator chain.
// Writes (Z, b1, b2, bi) partials; half 0 also stores +2z frags for p2.
__global__ __launch_bounds__(256, 8) void vq_p1(
    const float* __restrict__ z, const short* __restrict__ chA,
    const short* __restrict__ clA, const float* __restrict__ ncn2,
    float* __restrict__ out, float4* __restrict__ part) {
  const int lane = threadIdx.x & 63;
  const int pb = blockIdx.x >> 1;           // point block 0..1023
  const int h = blockIdx.x & 1;             // codebook half
  const int W = pb * 4 + (threadIdx.x >> 6);
  const int i0 = W * 32;
  const int col = lane & 31;
  const int hf = lane >> 5;

  // convert this tile's z -> +2z hi/lo frags; half 0 stores them for p2
  bf16x8 zh[4], zl[4];
  const float* zr = z + (size_t)(i0 + col) * 64 + hf * 8;
#pragma unroll
  for (int ks = 0; ks < 4; ks++) {
    float4 a = *(const float4*)(zr + ks * 16);
    float4 b = *(const float4*)(zr + ks * 16 + 4);
    float vv[8] = {a.x, a.y, a.z, a.w, b.x, b.y, b.z, b.w};
#pragma unroll
    for (int j = 0; j < 8; j++) {
      float vm = 2.0f * vv[j];
      unsigned short hh = f2bf(vm);
      zh[ks][j] = (short)hh;
      zl[ks][j] = (short)f2bf(vm - bf2f(hh));
    }
  }
  if (h == 0) {
    short* base = (short*)out + (size_t)W * 4096;  // O_QST == 0
#pragma unroll
    for (int ks = 0; ks < 4; ks++) {
      *(bf16x8*)(base + (ks * 64 + lane) * 8) = zh[ks];
      *(bf16x8*)(base + 2048 + (ks * 64 + lane) * 8) = zl[ks];
    }
  }

  float Zp = 0.0f, b1 = -3.0e38f, b2 = -3.0e38f;
  int bi = 0;

  const int t0 = h * 16;
  for (int t = t0; t < t0 + 16; t++) {
    float4 niv[4];
#pragma unroll
    for (int q = 0; q < 4; q++)
      niv[q] = *(const float4*)(ncn2 + t * 32 + 8 * q + 4 * hf);
    f32x16 acc;
#pragma unroll
    for (int r = 0; r < 16; r++) acc[r] = ((const float*)&niv[r >> 2])[r & 3];
    const short* ch = chA + ((size_t)(t * 4) * 64 + lane) * 8;
    const short* cl = clA + ((size_t)(t * 4) * 64 + lane) * 8;
#pragma unroll
    for (int ks = 0; ks < 4; ks++) {
      bf16x8 Ah = *(const bf16x8*)(ch + ks * 512);
      bf16x8 Al = *(const bf16x8*)(cl + ks * 512);
      acc = __builtin_amdgcn_mfma_f32_32x32x16_bf16(Ah, zh[ks], acc, 0, 0, 0);
      acc = __builtin_amdgcn_mfma_f32_32x32x16_bf16(Ah, zl[ks], acc, 0, 0, 0);
      acc = __builtin_amdgcn_mfma_f32_32x32x16_bf16(Al, zh[ks], acc, 0, 0, 0);
    }
#pragma unroll
    for (int r = 0; r < 16; r++) Zp += exp2f(acc[r]);
#pragma unroll
    for (int r = 0; r < 16; r++) {
      int code = t * 32 + (r & 3) + 8 * (r >> 2) + 4 * hf;
      float s = acc[r];
      b2 = fmaxf(fminf(s, b1), b2);  // second-best (b1 still old)
      bool gt = s > b1;
      b1 = gt ? s : b1;
      bi = gt ? code : bi;
    }
  }
  // merge the two half-wave partials (row split by hf)
  float Z2 = __shfl_xor(Zp, 32, 64);
  float b1o = __shfl_xor(b1, 32, 64);
  float b2o = __shfl_xor(b2, 32, 64);
  int bio = __shfl_xor(bi, 32, 64);
  float Zt = Zp + Z2;
  bool take = (b1o > b1) || (b1o == b1 && bio < bi);
  float g1 = fmaxf(b1, b1o);
  float g2 = fmaxf(fminf(b1, b1o), fmaxf(b2, b2o));
  int big = take ? bio : bi;
  if (hf == 0) part[(size_t)(i0 + col) * 2 + h] =
      make_float4(Zt, g1, g2, (float)big);
}

// ---------------------------------------------------------------------------
// Combine halves: ct, index, refine flags.  Half-0 codes are all < 512 so
// exact ties prefer half 0 (lower index) automatically.
__global__ __launch_bounds__(256) void vq_combine(
    const float4* __restrict__ part, float* __restrict__ ctA,
    float* __restrict__ out, int* __restrict__ nflag,
    int* __restrict__ list) {
  const int i = blockIdx.x * 256 + threadIdx.x;
  float4 a = part[(size_t)i * 2];
  float4 b = part[(size_t)i * 2 + 1];
  float Zt = a.x + b.x;
  bool take = b.y > a.y;
  float b1 = fmaxf(a.y, b.y);
  float b2 = fmaxf(fminf(a.y, b.y), fmaxf(a.z, b.z));
  ctA[i] = -__log2f(Zt);
  out[O_IDX + (size_t)i] = take ? b.w : a.w;
  if (b1 - b2 < DELTA) {
    int pos = atomicAdd(nflag, 1);
    list[pos] = i;
  }
}

// ---------------------------------------------------------------------------
// Refine: exact fp32 rescan of flagged (small-margin) points; patches O_IDX.
__global__ __launch_bounds__(256) void vq_refine(
    const float* __restrict__ z, const float* __restrict__ cb,
    const float* __restrict__ cn, const int* __restrict__ nflag,
    const int* __restrict__ list, float* __restrict__ out) {
  const int wave = blockIdx.x * 4 + (threadIdx.x >> 6);
  const int lane = threadIdx.x & 63;
  const int n = *nflag;
  for (int e = wave; e < n; e += 256) {
    const int i = list[e];
    const float4* zi4 = (const float4*)(z + (size_t)i * 64);
    float4 zq[16];
#pragma unroll
    for (int k = 0; k < 16; k++) zq[k] = zi4[k];
    float best = 3.0e38f;
    int bidx = 0;
    for (int cc = 0; cc < 16; cc++) {
      int c = cc * 64 + lane;
      const float4* cr = (const float4*)(cb + (size_t)c * 64);
      float dot0 = 0.0f, dot1 = 0.0f;
#pragma unroll
      for (int k = 0; k < 16; k += 2) {
        float4 a = cr[k];
        float4 bq = cr[k + 1];
        dot0 += zq[k].x * a.x + zq[k].y * a.y + zq[k].z * a.z + zq[k].w * a.w;
        dot1 += zq[k + 1].x * bq.x + zq[k + 1].y * bq.y + zq[k + 1].z * bq.z +
                zq[k + 1].w * bq.w;
      }
      float s = cn[c] - 2.0f * (dot0 + dot1);
      if (s < best) { best = s; bidx = c; }
    }
#pragma unroll
    for (int o = 32; o > 0; o >>= 1) {
      float ob = __shfl_xor(best, o, 64);
      int oi = __shfl_xor(bidx, o, 64);
      if (ob < best || (ob == best && oi < bidx)) { best = ob; bidx = oi; }
    }
    if (lane == 0) out[O_IDX + (size_t)i] = (float)bidx;
  }
}

// ---------------------------------------------------------------------------
// Pass 2: wave = 32 resident codes x 512 points (16 tiles).  Single acc
// chain, init = ct_i - cn2_j; su += 2^acc.
__global__ __launch_bounds__(256, 8) void vq_p2(
    const short* __restrict__ zF, const short* __restrict__ chA,
    const short* __restrict__ clA, const float* __restrict__ ncn2,
    const float* __restrict__ ctA, float* __restrict__ susum) {
  const int lane = threadIdx.x & 63;
  const int wv = threadIdx.x >> 6;
  const int b = blockIdx.x;
  // XCD swizzle: the 8 blocks sharing one point-group land on one XCD
  const int xcd = b & 7;
  const int sl = b >> 3;                  // 0..255
  const int pgrp = xcd * 32 + (sl >> 3);  // 0..255 point group (512 points)
  const int g = (sl & 7) * 4 + wv;        // 0..31 code tile
  const int col = lane & 31;
  const int hf = lane >> 5;

  bf16x8 Bh[4], Bl[4];
  const short* ch = chA + ((size_t)(g * 4) * 64 + lane) * 8;
  const short* cl = clA + ((size_t)(g * 4) * 64 + lane) * 8;
#pragma unroll
  for (int ks = 0; ks < 4; ks++) {
    Bh[ks] = *(const bf16x8*)(ch + ks * 512);
    Bl[ks] = *(const bf16x8*)(cl + ks * 512);
  }
  const float nc = ncn2[g * 32 + col];  // = -cn*log2e for this lane's code

  float su = 0.0f;
  for (int pt = 0; pt < 16; pt++) {
    const int T = pgrp * 16 + pt;
    const short* base = zF + (size_t)T * 4096;
    float4 ctv[4];
#pragma unroll
    for (int q = 0; q < 4; q++)
      ctv[q] = *(const float4*)(ctA + T * 32 + 8 * q + 4 * hf);
    f32x16 acc;
#pragma unroll
    for (int r = 0; r < 16; r++)
      acc[r] = ((const float*)&ctv[r >> 2])[r & 3] + nc;
#pragma unroll
    for (int ks = 0; ks < 4; ks++) {
      bf16x8 Ah = *(const bf16x8*)(base + (ks * 64 + lane) * 8);
      bf16x8 Al = *(const bf16x8*)(base + 2048 + (ks * 64 + lane) * 8);
      acc = __builtin_amdgcn_mfma_f32_32x32x16_bf16(Ah, Bh[ks], acc, 0, 0, 0);
      acc = __builtin_amdgcn_mfma_f32_32x32x16_bf16(Ah, Bl[ks], acc, 0, 0, 0);
      acc = __builtin_amdgcn_mfma_f32_32x32x16_bf16(Al, Bh[ks], acc, 0, 0, 0);
    }
#pragma unroll
    for (int r = 0; r < 16; r++) su += exp2f(acc[r]);
  }
  su += __shfl_xor(su, 32, 64);
  if (hf == 0) atomicAdd(&susum[g * 32 + col], su);
}

// ---------------------------------------------------------------------------
// Epilogue: 4 points per wave (float4/lane), grid-stride, idx prefetch,
// no LDS/barrier; one sqerr atomic per wave, counts atomic per point.
__global__ __launch_bounds__(256) void vq_epi(
    const float* __restrict__ z, const float* __restrict__ cb,
    float* __restrict__ out, float* __restrict__ counts,
    float* __restrict__ sqp) {
  const int lane = threadIdx.x & 63;
  const int wid = blockIdx.x * 4 + (threadIdx.x >> 6);  // 8192 waves
  const int seg = lane >> 4, sl = lane & 15;
  const float4* cb4 = (const float4*)cb;
  const float4* z4 = (const float4*)z;
  float4* o4 = (float4*)(out + O_QST);

  float acc = 0.0f;
  int bI_next = (int)out[O_IDX + (size_t)(wid * 4 + seg)];
#pragma unroll
  for (int it = 0; it < 4; it++) {
    const int ii = (wid + 8192 * it) * 4 + seg;
    const int bI = bI_next;
    if (it < 3)
      bI_next = (int)out[O_IDX + (size_t)((wid + 8192 * (it + 1)) * 4 + seg)];
    float4 c4 = cb4[(size_t)bI * 16 + sl];
    float4 zv = z4[(size_t)ii * 16 + sl];
    float ex = c4.x - zv.x, ey = c4.y - zv.y;
    float ez = c4.z - zv.z, ew = c4.w - zv.w;
    o4[(size_t)ii * 16 + sl] =
        make_float4(zv.x + ex, zv.y + ey, zv.z + ez, zv.w + ew);
    float s = ex * ex + ey * ey + ez * ez + ew * ew;
    s += __shfl_xor(s, 1, 64);
    s += __shfl_xor(s, 2, 64);
    s += __shfl_xor(s, 4, 64);
    s += __shfl_xor(s, 8, 64);
    if (sl == 0) atomicAdd(&counts[bI], 1.0f);
    acc += s;
  }
  acc += __shfl_xor(acc, 16, 64);
  acc += __shfl_xor(acc, 32, 64);
  if (lane == 0) atomicAdd(&sqp[wid & 255], acc);
}

// ---------------------------------------------------------------------------
__global__ __launch_bounds__(1024) void vq_final(
    const float* __restrict__ counts, const float* __restrict__ susum,
    const float* __restrict__ sqp, float* __restrict__ out) {
  __shared__ float red[16];
  __shared__ float red2[16];
  const int t = threadIdx.x;
  float cnt = counts[t];
  float usage = cnt * INV_N;
  out[O_USG + t] = usage;
  out[O_SU + t] = susum[t] * INV_N;
  float term = usage * logf(usage + 1e-8f);
  float sq = (t < 256) ? sqp[t] : 0.0f;
#pragma unroll
  for (int o = 32; o > 0; o >>= 1) {
    term += __shfl_xor(term, o, 64);
    sq += __shfl_xor(sq, o, 64);
  }
  if ((t & 63) == 0) {
    red[t >> 6] = term;
    red2[t >> 6] = sq;
  }
  __syncthreads();
  if (t < 16) {
    float v = red[t];
    float s2 = red2[t];
#pragma unroll
    for (int o = 8; o > 0; o >>= 1) {
      v += __shfl_xor(v, o, 64);
      s2 += __shfl_xor(s2, o, 64);
    }
    if (t == 0) {
      float ppl = __expf(-v);
      float cbl = s2 * INV_ELEMS;
      out[O_LOSS] = cbl + 0.25f * cbl;
      out[O_CBL] = cbl;
      out[O_CML] = cbl;
      out[O_PPL] = ppl;
    }
  }
}

// ---------------------------------------------------------------------------
extern "C" void kernel_launch(void* const* d_in, const int* in_sizes, int n_in,
                              void* d_out, int out_size, void* d_ws,
                              size_t ws_size, hipStream_t stream) {
  const float* z = (const float*)d_in[0];
  const float* cb = (const float*)d_in[1];
  float* ws = (float*)d_ws;
  float* cn = ws;
  float* counts = ws + 1024;
  float* susum = ws + 2048;
  float* sqp = ws + 3072;
  int* nflag = (int*)(ws + 3328);
  float* ncn2 = ws + 3584;
  short* chA = (short*)(ws + 4608);
  short* clA = (short*)(ws + 37376);
  float* ctA = ws + 70144;
  int* list = (int*)(ws + 201216);
  float4* part = (float4*)(ws + 332288);
  float* out = (float*)d_out;

  // zero counts+susum+sqp+nflag in one memset
  (void)hipMemsetAsync(counts, 0, (1024 + 1024 + 256 + 1) * sizeof(float),
                       stream);

  vq_prep<<<256, 256, 0, stream>>>(cb, cn, ncn2, chA, clA);
  vq_p1<<<2048, 256, 0, stream>>>(z, chA, clA, ncn2, out, part);
  vq_combine<<<N / 256, 256, 0, stream>>>(part, ctA, out, nflag, list);
  vq_refine<<<64, 256, 0, stream>>>(z, cb, cn, nflag, list, out);
  vq_p2<<<2048, 256, 0, stream>>>((const short*)out, chA, clA, ncn2, ctA,
                                  susum);
  vq_epi<<<2048, 256, 0, stream>>>(z, cb, out, counts, sqp);
  vq_final<<<1, 1024, 0, stream>>>(counts, susum, sqp, out);
}

// Round 8
// 363.459 us; speedup vs baseline: 1.2487x; 1.2487x over previous
//
#include <hip/hip_runtime.h>

constexpr int K = 1024;        // num codes
constexpr int D = 64;          // dim
constexpr int N = 131072;      // 32*4096 points
constexpr float INV_N = 1.0f / 131072.0f;
constexpr float INV_ELEMS = 1.0f / 8388608.0f;  // N*D
constexpr float LOG2E = 1.4426950408889634f;
constexpr float DELTA = 0.01f;  // refine margin in log2e-scaled units

// Output layout (flat float32, return order)
constexpr size_t O_QST  = 0;          // [N*D] quantized_st
constexpr size_t O_LOSS = 8388608;    // [1]
constexpr size_t O_IDX  = 8388609;    // [N]
constexpr size_t O_CBL  = 8519681;    // [1]
constexpr size_t O_CML  = 8519682;    // [1]
constexpr size_t O_PPL  = 8519683;    // [1]
constexpr size_t O_USG  = 8519684;    // [1024]
constexpr size_t O_SU   = 8520708;    // [1024]

// Workspace (float offsets), ~5.6 MB total:
//  [0,1024)        cn     raw fp32 codebook norms (exact rescan)
//  [1024,2048)     counts
//  [2048,3072)     susum
//  [3072,3328)     sqp    spread sqerr partials
//  [3328]          nflag  (int) flagged-point counter
//  [3584,4608)     ncn2   -cn * log2e (acc-init)
//  [4608,37376)    chA    bf16 hi split of codebook*log2e, frag layout
//  [37376,70144)   clA    bf16 lo split
//  [70144,201216)  ctA    per-point ct2 = -log2(Z')
//  [201216,332288) list   (int) flagged point ids
//  [332288,1380864) part  float4[N*2]: per (point, cb-half) partials
//                         (Z, b1, b2, bi)

// qst slots double as z-frag storage between p1 and epi:
// tile t (32 points): shorts base = t*4096; hi frag at (ks*64+lane)*8,
// lo frag at 2048 + (ks*64+lane)*8.  Holds split of (+2*z).

typedef __attribute__((ext_vector_type(8))) short bf16x8;
typedef __attribute__((ext_vector_type(16))) float f32x16;

__device__ inline unsigned short f2bf(float f) {  // RTNE fp32->bf16
  unsigned u = __float_as_uint(f);
  return (unsigned short)((u + 0x7FFF + ((u >> 16) & 1)) >> 16);
}
__device__ inline float bf2f(unsigned short h) {
  return __uint_as_float(((unsigned)h) << 16);
}

// ---------------------------------------------------------------------------
// Fused norms + frag prep: wave = one code (64 consecutive gids).
__global__ __launch_bounds__(256) void vq_prep(const float* __restrict__ cb,
                                               float* __restrict__ cn,
                                               float* __restrict__ ncn2,
                                               short* __restrict__ chA,
                                               short* __restrict__ clA) {
  const int gid = blockIdx.x * 256 + threadIdx.x;  // 65536
  const int c = gid >> 6, d = gid & 63;            // c wave-uniform
  float v = cb[gid];
  float s = v * v;
#pragma unroll
  for (int o = 32; o > 0; o >>= 1) s += __shfl_xor(s, o, 64);
  if (d == 0) {
    cn[c] = s;
    ncn2[c] = -s * LOG2E;
  }
  float vb = v * LOG2E;
  unsigned short h = f2bf(vb);
  unsigned short l = f2bf(vb - bf2f(h));
  const int tile = c >> 5, ks = d >> 4, hff = (d >> 3) & 1, j = d & 7;
  const int lane = hff * 32 + (c & 31);
  const size_t off = ((size_t)((tile * 4 + ks) * 64 + lane)) * 8 + j;
  chA[off] = (short)h;
  clA[off] = (short)l;
}

// ---------------------------------------------------------------------------
// Pass 1: block = 32 points x HALF the codebook (h = blockIdx&1).
// acc = -s = 2z.c*log2e - cn2, single fp32 MFMA accumulator chain.
// Writes (Z, b1, b2, bi) partials; half 0 also stores +2z frags for p2.
// NOTE: launch_bounds (256,4) — forcing 8 waves/EU (R7) spilled at 32 VGPR;
// natural allocation ~48-64 VGPR still allows 8 waves/SIMD residency.
__global__ __launch_bounds__(256, 4) void vq_p1(
    const float* __restrict__ z, const short* __restrict__ chA,
    const short* __restrict__ clA, const float* __restrict__ ncn2,
    float* __restrict__ out, float4* __restrict__ part) {
  const int lane = threadIdx.x & 63;
  const int pb = blockIdx.x >> 1;           // point block 0..1023
  const int h = blockIdx.x & 1;             // codebook half
  const int W = pb * 4 + (threadIdx.x >> 6);
  const int i0 = W * 32;
  const int col = lane & 31;
  const int hf = lane >> 5;

  // convert this tile's z -> +2z hi/lo frags; half 0 stores them for p2
  bf16x8 zh[4], zl[4];
  const float* zr = z + (size_t)(i0 + col) * 64 + hf * 8;
#pragma unroll
  for (int ks = 0; ks < 4; ks++) {
    float4 a = *(const float4*)(zr + ks * 16);
    float4 b = *(const float4*)(zr + ks * 16 + 4);
    float vv[8] = {a.x, a.y, a.z, a.w, b.x, b.y, b.z, b.w};
#pragma unroll
    for (int j = 0; j < 8; j++) {
      float vm = 2.0f * vv[j];
      unsigned short hh = f2bf(vm);
      zh[ks][j] = (short)hh;
      zl[ks][j] = (short)f2bf(vm - bf2f(hh));
    }
  }
  if (h == 0) {
    short* base = (short*)out + (size_t)W * 4096;  // O_QST == 0
#pragma unroll
    for (int ks = 0; ks < 4; ks++) {
      *(bf16x8*)(base + (ks * 64 + lane) * 8) = zh[ks];
      *(bf16x8*)(base + 2048 + (ks * 64 + lane) * 8) = zl[ks];
    }
  }

  float Zp = 0.0f, b1 = -3.0e38f, b2 = -3.0e38f;
  int bi = 0;

  const int t0 = h * 16;
  for (int t = t0; t < t0 + 16; t++) {
    float4 niv[4];
#pragma unroll
    for (int q = 0; q < 4; q++)
      niv[q] = *(const float4*)(ncn2 + t * 32 + 8 * q + 4 * hf);
    f32x16 acc;
#pragma unroll
    for (int r = 0; r < 16; r++) acc[r] = ((const float*)&niv[r >> 2])[r & 3];
    const short* ch = chA + ((size_t)(t * 4) * 64 + lane) * 8;
    const short* cl = clA + ((size_t)(t * 4) * 64 + lane) * 8;
#pragma unroll
    for (int ks = 0; ks < 4; ks++) {
      bf16x8 Ah = *(const bf16x8*)(ch + ks * 512);
      bf16x8 Al = *(const bf16x8*)(cl + ks * 512);
      acc = __builtin_amdgcn_mfma_f32_32x32x16_bf16(Ah, zh[ks], acc, 0, 0, 0);
      acc = __builtin_amdgcn_mfma_f32_32x32x16_bf16(Ah, zl[ks], acc, 0, 0, 0);
      acc = __builtin_amdgcn_mfma_f32_32x32x16_bf16(Al, zh[ks], acc, 0, 0, 0);
    }
#pragma unroll
    for (int r = 0; r < 16; r++) Zp += exp2f(acc[r]);
#pragma unroll
    for (int r = 0; r < 16; r++) {
      int code = t * 32 + (r & 3) + 8 * (r >> 2) + 4 * hf;
      float s = acc[r];
      b2 = fmaxf(fminf(s, b1), b2);  // second-best (b1 still old)
      bool gt = s > b1;
      b1 = gt ? s : b1;
      bi = gt ? code : bi;
    }
  }
  // merge the two half-wave partials (row split by hf)
  float Z2 = __shfl_xor(Zp, 32, 64);
  float b1o = __shfl_xor(b1, 32, 64);
  float b2o = __shfl_xor(b2, 32, 64);
  int bio = __shfl_xor(bi, 32, 64);
  float Zt = Zp + Z2;
  bool take = (b1o > b1) || (b1o == b1 && bio < bi);
  float g1 = fmaxf(b1, b1o);
  float g2 = fmaxf(fminf(b1, b1o), fmaxf(b2, b2o));
  int big = take ? bio : bi;
  if (hf == 0) part[(size_t)(i0 + col) * 2 + h] =
      make_float4(Zt, g1, g2, (float)big);
}

// ---------------------------------------------------------------------------
// Combine halves: ct, index, refine flags.  Half-0 codes are all < 512 so
// exact ties prefer half 0 (lower index) automatically.
__global__ __launch_bounds__(256) void vq_combine(
    const float4* __restrict__ part, float* __restrict__ ctA,
    float* __restrict__ out, int* __restrict__ nflag,
    int* __restrict__ list) {
  const int i = blockIdx.x * 256 + threadIdx.x;
  float4 a = part[(size_t)i * 2];
  float4 b = part[(size_t)i * 2 + 1];
  float Zt = a.x + b.x;
  bool take = b.y > a.y;
  float b1 = fmaxf(a.y, b.y);
  float b2 = fmaxf(fminf(a.y, b.y), fmaxf(a.z, b.z));
  ctA[i] = -__log2f(Zt);
  out[O_IDX + (size_t)i] = take ? b.w : a.w;
  if (b1 - b2 < DELTA) {
    int pos = atomicAdd(nflag, 1);
    list[pos] = i;
  }
}

// ---------------------------------------------------------------------------
// Refine: exact fp32 rescan of flagged (small-margin) points; patches O_IDX.
__global__ __launch_bounds__(256) void vq_refine(
    const float* __restrict__ z, const float* __restrict__ cb,
    const float* __restrict__ cn, const int* __restrict__ nflag,
    const int* __restrict__ list, float* __restrict__ out) {
  const int wave = blockIdx.x * 4 + (threadIdx.x >> 6);
  const int lane = threadIdx.x & 63;
  const int n = *nflag;
  for (int e = wave; e < n; e += 256) {
    const int i = list[e];
    const float4* zi4 = (const float4*)(z + (size_t)i * 64);
    float4 zq[16];
#pragma unroll
    for (int k = 0; k < 16; k++) zq[k] = zi4[k];
    float best = 3.0e38f;
    int bidx = 0;
    for (int cc = 0; cc < 16; cc++) {
      int c = cc * 64 + lane;
      const float4* cr = (const float4*)(cb + (size_t)c * 64);
      float dot0 = 0.0f, dot1 = 0.0f;
#pragma unroll
      for (int k = 0; k < 16; k += 2) {
        float4 a = cr[k];
        float4 bq = cr[k + 1];
        dot0 += zq[k].x * a.x + zq[k].y * a.y + zq[k].z * a.z + zq[k].w * a.w;
        dot1 += zq[k + 1].x * bq.x + zq[k + 1].y * bq.y + zq[k + 1].z * bq.z +
                zq[k + 1].w * bq.w;
      }
      float s = cn[c] - 2.0f * (dot0 + dot1);
      if (s < best) { best = s; bidx = c; }
    }
#pragma unroll
    for (int o = 32; o > 0; o >>= 1) {
      float ob = __shfl_xor(best, o, 64);
      int oi = __shfl_xor(bidx, o, 64);
      if (ob < best || (ob == best && oi < bidx)) { best = ob; bidx = oi; }
    }
    if (lane == 0) out[O_IDX + (size_t)i] = (float)bidx;
  }
}

// ---------------------------------------------------------------------------
// Pass 2: wave = 32 resident codes x 512 points (16 tiles).  Single acc
// chain, init = ct_i - cn2_j; su += 2^acc.
__global__ __launch_bounds__(256, 4) void vq_p2(
    const short* __restrict__ zF, const short* __restrict__ chA,
    const short* __restrict__ clA, const float* __restrict__ ncn2,
    const float* __restrict__ ctA, float* __restrict__ susum) {
  const int lane = threadIdx.x & 63;
  const int wv = threadIdx.x >> 6;
  const int b = blockIdx.x;
  // XCD swizzle: the 8 blocks sharing one point-group land on one XCD
  const int xcd = b & 7;
  const int sl = b >> 3;                  // 0..255
  const int pgrp = xcd * 32 + (sl >> 3);  // 0..255 point group (512 points)
  const int g = (sl & 7) * 4 + wv;        // 0..31 code tile
  const int col = lane & 31;
  const int hf = lane >> 5;

  bf16x8 Bh[4], Bl[4];
  const short* ch = chA + ((size_t)(g * 4) * 64 + lane) * 8;
  const short* cl = clA + ((size_t)(g * 4) * 64 + lane) * 8;
#pragma unroll
  for (int ks = 0; ks < 4; ks++) {
    Bh[ks] = *(const bf16x8*)(ch + ks * 512);
    Bl[ks] = *(const bf16x8*)(cl + ks * 512);
  }
  const float nc = ncn2[g * 32 + col];  // = -cn*log2e for this lane's code

  float su = 0.0f;
  for (int pt = 0; pt < 16; pt++) {
    const int T = pgrp * 16 + pt;
    const short* base = zF + (size_t)T * 4096;
    float4 ctv[4];
#pragma unroll
    for (int q = 0; q < 4; q++)
      ctv[q] = *(const float4*)(ctA + T * 32 + 8 * q + 4 * hf);
    f32x16 acc;
#pragma unroll
    for (int r = 0; r < 16; r++)
      acc[r] = ((const float*)&ctv[r >> 2])[r & 3] + nc;
#pragma unroll
    for (int ks = 0; ks < 4; ks++) {
      bf16x8 Ah = *(const bf16x8*)(base + (ks * 64 + lane) * 8);
      bf16x8 Al = *(const bf16x8*)(base + 2048 + (ks * 64 + lane) * 8);
      acc = __builtin_amdgcn_mfma_f32_32x32x16_bf16(Ah, Bh[ks], acc, 0, 0, 0);
      acc = __builtin_amdgcn_mfma_f32_32x32x16_bf16(Ah, Bl[ks], acc, 0, 0, 0);
      acc = __builtin_amdgcn_mfma_f32_32x32x16_bf16(Al, Bh[ks], acc, 0, 0, 0);
    }
#pragma unroll
    for (int r = 0; r < 16; r++) su += exp2f(acc[r]);
  }
  su += __shfl_xor(su, 32, 64);
  if (hf == 0) atomicAdd(&susum[g * 32 + col], su);
}

// ---------------------------------------------------------------------------
// Epilogue: 4 points per wave (float4/lane), grid-stride, idx prefetch,
// no LDS/barrier; one sqerr atomic per wave, counts atomic per point.
__global__ __launch_bounds__(256) void vq_epi(
    const float* __restrict__ z, const float* __restrict__ cb,
    float* __restrict__ out, float* __restrict__ counts,
    float* __restrict__ sqp) {
  const int lane = threadIdx.x & 63;
  const int wid = blockIdx.x * 4 + (threadIdx.x >> 6);  // 8192 waves
  const int seg = lane >> 4, sl = lane & 15;
  const float4* cb4 = (const float4*)cb;
  const float4* z4 = (const float4*)z;
  float4* o4 = (float4*)(out + O_QST);

  float acc = 0.0f;
  int bI_next = (int)out[O_IDX + (size_t)(wid * 4 + seg)];
#pragma unroll
  for (int it = 0; it < 4; it++) {
    const int ii = (wid + 8192 * it) * 4 + seg;
    const int bI = bI_next;
    if (it < 3)
      bI_next = (int)out[O_IDX + (size_t)((wid + 8192 * (it + 1)) * 4 + seg)];
    float4 c4 = cb4[(size_t)bI * 16 + sl];
    float4 zv = z4[(size_t)ii * 16 + sl];
    float ex = c4.x - zv.x, ey = c4.y - zv.y;
    float ez = c4.z - zv.z, ew = c4.w - zv.w;
    o4[(size_t)ii * 16 + sl] =
        make_float4(zv.x + ex, zv.y + ey, zv.z + ez, zv.w + ew);
    float s = ex * ex + ey * ey + ez * ez + ew * ew;
    s += __shfl_xor(s, 1, 64);
    s += __shfl_xor(s, 2, 64);
    s += __shfl_xor(s, 4, 64);
    s += __shfl_xor(s, 8, 64);
    if (sl == 0) atomicAdd(&counts[bI], 1.0f);
    acc += s;
  }
  acc += __shfl_xor(acc, 16, 64);
  acc += __shfl_xor(acc, 32, 64);
  if (lane == 0) atomicAdd(&sqp[wid & 255], acc);
}

// ---------------------------------------------------------------------------
__global__ __launch_bounds__(1024) void vq_final(
    const float* __restrict__ counts, const float* __restrict__ susum,
    const float* __restrict__ sqp, float* __restrict__ out) {
  __shared__ float red[16];
  __shared__ float red2[16];
  const int t = threadIdx.x;
  float cnt = counts[t];
  float usage = cnt * INV_N;
  out[O_USG + t] = usage;
  out[O_SU + t] = susum[t] * INV_N;
  float term = usage * logf(usage + 1e-8f);
  float sq = (t < 256) ? sqp[t] : 0.0f;
#pragma unroll
  for (int o = 32; o > 0; o >>= 1) {
    term += __shfl_xor(term, o, 64);
    sq += __shfl_xor(sq, o, 64);
  }
  if ((t & 63) == 0) {
    red[t >> 6] = term;
    red2[t >> 6] = sq;
  }
  __syncthreads();
  if (t < 16) {
    float v = red[t];
    float s2 = red2[t];
#pragma unroll
    for (int o = 8; o > 0; o >>= 1) {
      v += __shfl_xor(v, o, 64);
      s2 += __shfl_xor(s2, o, 64);
    }
    if (t == 0) {
      float ppl = __expf(-v);
      float cbl = s2 * INV_ELEMS;
      out[O_LOSS] = cbl + 0.25f * cbl;
      out[O_CBL] = cbl;
      out[O_CML] = cbl;
      out[O_PPL] = ppl;
    }
  }
}

// ---------------------------------------------------------------------------
extern "C" void kernel_launch(void* const* d_in, const int* in_sizes, int n_in,
                              void* d_out, int out_size, void* d_ws,
                              size_t ws_size, hipStream_t stream) {
  const float* z = (const float*)d_in[0];
  const float* cb = (const float*)d_in[1];
  float* ws = (float*)d_ws;
  float* cn = ws;
  float* counts = ws + 1024;
  float* susum = ws + 2048;
  float* sqp = ws + 3072;
  int* nflag = (int*)(ws + 3328);
  float* ncn2 = ws + 3584;
  short* chA = (short*)(ws + 4608);
  short* clA = (short*)(ws + 37376);
  float* ctA = ws + 70144;
  int* list = (int*)(ws + 201216);
  float4* part = (float4*)(ws + 332288);
  float* out = (float*)d_out;

  // zero counts+susum+sqp+nflag in one memset
  (void)hipMemsetAsync(counts, 0, (1024 + 1024 + 256 + 1) * sizeof(float),
                       stream);

  vq_prep<<<256, 256, 0, stream>>>(cb, cn, ncn2, chA, clA);
  vq_p1<<<2048, 256, 0, stream>>>(z, chA, clA, ncn2, out, part);
  vq_combine<<<N / 256, 256, 0, stream>>>(part, ctA, out, nflag, list);
  vq_refine<<<64, 256, 0, stream>>>(z, cb, cn, nflag, list, out);
  vq_p2<<<2048, 256, 0, stream>>>((const short*)out, chA, clA, ncn2, ctA,
                                  susum);
  vq_epi<<<2048, 256, 0, stream>>>(z, cb, out, counts, sqp);
  vq_final<<<1, 1024, 0, stream>>>(counts, susum, sqp, out);
}